// Round 10
// baseline (59926.703 us; speedup 1.0000x reference)
//
#include <hip/hip_runtime.h>
#include <hip/hip_bf16.h>

#define BATCH 16384
#define TSTEPS 101
#define HDIM 512
#define GDIM 2048
#define NBLK 512

typedef __attribute__((ext_vector_type(8))) short s16x8;
typedef __attribute__((ext_vector_type(4))) float f32x4;

__device__ __forceinline__ float sigm(float x){
  return __builtin_amdgcn_rcpf(1.0f + __expf(-x));
}
__device__ __forceinline__ float tanhx(float x){
  float e = __expf(2.0f*x);
  return 1.0f - 2.0f*__builtin_amdgcn_rcpf(e + 1.0f);
}

__device__ __forceinline__ void gload16(const void* g, void* l){
  __builtin_amdgcn_global_load_lds((const __attribute__((address_space(1))) unsigned int*)g,
                                   (__attribute__((address_space(3))) unsigned int*)l, 16, 0, 0);
}

// device-scope grid barrier (generation-based), proven R5/R9. 512 blocks, 2/CU guaranteed
// (64KB LDS -> 2 blocks/CU; regs <= 512/wave always; 16 waves/CU <= 32).
__device__ __forceinline__ void gsync(unsigned* cnt, unsigned* gen){
  __syncthreads();
  if (threadIdx.x == 0){
    __threadfence();
    unsigned g = __hip_atomic_load(gen, __ATOMIC_RELAXED, __HIP_MEMORY_SCOPE_AGENT);
    unsigned prev = __hip_atomic_fetch_add(cnt, 1u, __ATOMIC_ACQ_REL, __HIP_MEMORY_SCOPE_AGENT);
    if (prev == NBLK - 1u){
      __hip_atomic_store(cnt, 0u, __ATOMIC_RELAXED, __HIP_MEMORY_SCOPE_AGENT);
      __hip_atomic_store(gen, g + 1u, __ATOMIC_RELEASE, __HIP_MEMORY_SCOPE_AGENT);
    } else {
      while (__hip_atomic_load(gen, __ATOMIC_ACQUIRE, __HIP_MEMORY_SCOPE_AGENT) == g){
        __builtin_amdgcn_s_sleep(8);
      }
    }
    __threadfence();
  }
  __syncthreads();
}

// Persistent LSTM, R2 GEMM engine inside: 512 blocks x 512 thr (8 waves), 64KB LDS,
// 2 blocks/CU. Block = (panel of 256 rows, 64 hcols x 4 gates); c in VGPRs for all
// 101 steps; h through global, XCD-pinned panels; gsync between steps.
// Wave = 64 rows x 128 gatecols (4 gates x 32 hcols); 16x16x32 MFMA, R2 frag layout.
__global__ __launch_bounds__(512, 4) void lstm_fused(
    const float* __restrict__ bx,
    const float* __restrict__ Wih,
    const float* __restrict__ bcomb,
    const __hip_bfloat16* __restrict__ wbf,
    __hip_bfloat16* __restrict__ hb0,
    __hip_bfloat16* __restrict__ hb1,
    unsigned* cnt, unsigned* gen)
{
  __shared__ short sA[256*64];   // 256 batch rows x 64 k   (32 KB)
  __shared__ short sB[256*64];   // 256 gaterows  x 64 k    (32 KB)
  const int tid = threadIdx.x;
  const int l = tid & 63, w = tid >> 6;
  const int lr = l & 15, lk = l >> 4;
  const int wr = w >> 1, wc = w & 1;       // wave: 64-row quarter / 32-hcol half

  const int b = blockIdx.x;
  const int panel = (b & 7)*8 + ((b >> 3) & 7);  // 64 panels x 256 rows, XCD-pinned
  const int j = b >> 6;                          // 8 col-slices x 64 hcols

  // staging addresses (A as offsets: hin alternates; B full pointers)
  size_t aoff[4]; int adst[4];
  const __hip_bfloat16* bsrc[4]; int bdst[4];
  #pragma unroll
  for (int i = 0; i < 4; ++i){
    int c = i*512 + tid;                 // 2048 chunks each
    int row = c >> 3, s = c & 7;
    int kc = s ^ (row & 7);
    aoff[i] = (size_t)(panel*256 + row)*HDIM + kc*8;
    adst[i] = c*8;
    int g = row >> 6, hcw = row & 63;
    bsrc[i] = wbf + (size_t)(g*HDIM + j*64 + hcw)*HDIM + kc*8;
    bdst[i] = c*8;
  }

  float cst[4][2][4];                    // c state in regs (static-indexed)
  #pragma unroll
  for (int m = 0; m < 4; ++m)
    #pragma unroll
    for (int n = 0; n < 2; ++n)
      #pragma unroll
      for (int rg = 0; rg < 4; ++rg) cst[m][n][rg] = 0.f;

  const float* bxb = bx;

  for (int t = 0; t < TSTEPS; ++t){
    const __hip_bfloat16* hin = (t & 1) ? hb1 : hb0;
    __hip_bfloat16*      hout = (t & 1) ? hb0 : hb1;

    f32x4 acc[4][4][2] = {};             // [gate][m][n]
    if (t > 0){
      for (int kt = 0; kt < 8; ++kt){
        const int k0 = kt*64;
        __syncthreads();
        #pragma unroll
        for (int i = 0; i < 4; ++i) gload16(hin + aoff[i] + k0, &sA[adst[i]]);
        #pragma unroll
        for (int i = 0; i < 4; ++i) gload16(bsrc[i] + k0, &sB[bdst[i]]);
        __syncthreads();
        #pragma unroll
        for (int kk = 0; kk < 2; ++kk){
          s16x8 av[4];
          #pragma unroll
          for (int m = 0; m < 4; ++m){
            int row = wr*64 + m*16 + lr;
            int slot = row*8 + ((kk*4 + lk) ^ (row & 7));
            av[m] = *(const s16x8*)&sA[slot*8];
          }
          #pragma unroll
          for (int g = 0; g < 4; ++g){
            #pragma unroll
            for (int n = 0; n < 2; ++n){
              int rB = g*64 + wc*32 + n*16 + lr;
              int slot = rB*8 + ((kk*4 + lk) ^ (rB & 7));
              s16x8 bv = *(const s16x8*)&sB[slot*8];
              #pragma unroll
              for (int m = 0; m < 4; ++m)
                acc[g][m][n] = __builtin_amdgcn_mfma_f32_16x16x32_bf16(av[m], bv, acc[g][m][n], 0, 0, 0);
            }
          }
        }
      }
    }

    // ---- epilogue: x-projection + bias + cell update (c in regs) ----
    float4 wv[4][2]; float bc4[4][2];
    #pragma unroll
    for (int g = 0; g < 4; ++g){
      #pragma unroll
      for (int n = 0; n < 2; ++n){
        int col = j*64 + wc*32 + n*16 + lr;
        int gc = g*HDIM + col;
        wv[g][n]  = *(const float4*)(Wih + (size_t)gc*4);
        bc4[g][n] = bcomb[gc];
      }
    }
    #pragma unroll
    for (int m = 0; m < 4; ++m){
      #pragma unroll
      for (int rg = 0; rg < 4; ++rg){
        int r = panel*256 + wr*64 + m*16 + lk*4 + rg;
        float4 xv = *(const float4*)(bxb + ((size_t)r*TSTEPS + t)*4);
        #pragma unroll
        for (int n = 0; n < 2; ++n){
          int col = j*64 + wc*32 + n*16 + lr;
          float pi = acc[0][m][n][rg] + bc4[0][n] + xv.x*wv[0][n].x + xv.y*wv[0][n].y + xv.z*wv[0][n].z + xv.w*wv[0][n].w;
          float pf = acc[1][m][n][rg] + bc4[1][n] + xv.x*wv[1][n].x + xv.y*wv[1][n].y + xv.z*wv[1][n].z + xv.w*wv[1][n].w;
          float pg = acc[2][m][n][rg] + bc4[2][n] + xv.x*wv[2][n].x + xv.y*wv[2][n].y + xv.z*wv[2][n].z + xv.w*wv[2][n].w;
          float po = acc[3][m][n][rg] + bc4[3][n] + xv.x*wv[3][n].x + xv.y*wv[3][n].y + xv.z*wv[3][n].z + xv.w*wv[3][n].w;
          float iv = sigm(pi), fv = sigm(pf), gv = tanhx(pg), ov = sigm(po);
          float cn = fv*cst[m][n][rg] + iv*gv;
          cst[m][n][rg] = cn;
          hout[(size_t)r*HDIM + col] = __float2bfloat16(ov*tanhx(cn));
        }
      }
    }
    if (t < TSTEPS - 1) gsync(cnt, gen);
  }
}

__global__ void prep(const float* __restrict__ Whh, const float* __restrict__ W1,
                     const float* __restrict__ bih, const float* __restrict__ bhh,
                     __hip_bfloat16* __restrict__ wbf, __hip_bfloat16* __restrict__ w1bf,
                     float* __restrict__ bcomb){
  int i = blockIdx.x*256 + threadIdx.x;
  if (i < GDIM*HDIM) wbf[i] = __float2bfloat16(Whh[i]);
  if (i < HDIM*HDIM) w1bf[i] = __float2bfloat16(W1[i]);
  if (i < GDIM) bcomb[i] = bih[i] + bhh[i];
}

// x = relu(hT @ W1^T + b1), bf16 MFMA, fp32 out. Block 128x128, wave 32x128.
__global__ __launch_bounds__(256) void mlp1(const __hip_bfloat16* __restrict__ hT,
                                            const __hip_bfloat16* __restrict__ w1bf,
                                            const float* __restrict__ b1, float* __restrict__ xout){
  __shared__ short sA[128*64];
  __shared__ short sB[128*64];
  const int tid = threadIdx.x;
  const int l = tid & 63, w = tid >> 6;
  const int lr = l & 15, lk = l >> 4;
  const int r0 = blockIdx.x * 128, c0 = blockIdx.y * 128;

  f32x4 acc[2][8] = {};
  for (int k0 = 0; k0 < HDIM; k0 += 64){
    __syncthreads();
    #pragma unroll
    for (int i = 0; i < 4; ++i){
      int cch = i*256 + tid;
      int row = cch >> 3, kc = cch & 7;
      int kcs = kc ^ (row & 7);
      gload16(hT + (size_t)(r0 + row)*HDIM + k0 + kcs*8, &sA[cch*8]);
    }
    #pragma unroll
    for (int i = 0; i < 4; ++i){
      int cch = i*256 + tid;
      int row = cch >> 3, kc = cch & 7;
      int kcs = kc ^ (row & 7);
      gload16(w1bf + (size_t)(c0 + row)*HDIM + k0 + kcs*8, &sB[cch*8]);
    }
    __syncthreads();
    #pragma unroll
    for (int kk = 0; kk < 2; ++kk){
      s16x8 av[2];
      #pragma unroll
      for (int m = 0; m < 2; ++m){
        int row = w*32 + m*16 + lr;
        int slot = row*8 + ((kk*4 + lk) ^ (row & 7));
        av[m] = *(const s16x8*)&sA[slot*8];
      }
      #pragma unroll
      for (int n = 0; n < 8; ++n){
        int rB = n*16 + lr;
        int slot = rB*8 + ((kk*4 + lk) ^ (rB & 7));
        s16x8 bv = *(const s16x8*)&sB[slot*8];
        #pragma unroll
        for (int m = 0; m < 2; ++m)
          acc[m][n] = __builtin_amdgcn_mfma_f32_16x16x32_bf16(av[m], bv, acc[m][n], 0, 0, 0);
      }
    }
  }
  #pragma unroll
  for (int m = 0; m < 2; ++m){
    #pragma unroll
    for (int rg = 0; rg < 4; ++rg){
      int r = r0 + w*32 + m*16 + lk*4 + rg;
      #pragma unroll
      for (int n = 0; n < 8; ++n){
        int c = c0 + n*16 + lr;
        float v = acc[m][n][rg] + b1[c];
        xout[(size_t)r*HDIM + c] = v > 0.f ? v : 0.f;
      }
    }
  }
}

// out[b] = x[b,:] . W2[0:512] + a[b]*W2[512] + b2 ; one wave per row
__global__ __launch_bounds__(256) void mlp2(const float* __restrict__ x, const float* __restrict__ a,
                                            const float* __restrict__ W2, const float* __restrict__ b2,
                                            float* __restrict__ out){
  const int wi = threadIdx.x >> 6, l = threadIdx.x & 63;
  const int b = blockIdx.x*4 + wi;
  const float* xr = x + (size_t)b*HDIM;
  float4 v0 = *(const float4*)(xr + l*8);
  float4 v1 = *(const float4*)(xr + l*8 + 4);
  float4 w0 = *(const float4*)(W2 + l*8);
  float4 w1 = *(const float4*)(W2 + l*8 + 4);
  float s = v0.x*w0.x + v0.y*w0.y + v0.z*w0.z + v0.w*w0.w
          + v1.x*w1.x + v1.y*w1.y + v1.z*w1.z + v1.w*w1.w;
  #pragma unroll
  for (int off = 32; off > 0; off >>= 1) s += __shfl_down(s, off);
  if (l == 0) out[b] = s + a[b]*W2[HDIM] + b2[0];
}

extern "C" void kernel_launch(void* const* d_in, const int* in_sizes, int n_in,
                              void* d_out, int out_size, void* d_ws, size_t ws_size,
                              hipStream_t stream){
  const float* bx  = (const float*)d_in[0];
  const float* ba  = (const float*)d_in[1];
  const float* Wih = (const float*)d_in[2];
  const float* Whh = (const float*)d_in[3];
  const float* bih = (const float*)d_in[4];
  const float* bhh = (const float*)d_in[5];
  const float* W1  = (const float*)d_in[6];
  const float* b1  = (const float*)d_in[7];
  const float* W2  = (const float*)d_in[8];
  const float* b2  = (const float*)d_in[9];
  float* out = (float*)d_out;

  char* ws = (char*)d_ws;
  __hip_bfloat16* wbf   = (__hip_bfloat16*)(ws);              // 2 MB
  __hip_bfloat16* w1bf  = (__hip_bfloat16*)(ws + 2097152);    // 512 KB
  float*          bcomb = (float*)(ws + 2621440);             // 8 KB
  __hip_bfloat16* hb0   = (__hip_bfloat16*)(ws + 2629632);    // 16 MB
  __hip_bfloat16* hb1   = (__hip_bfloat16*)(ws + 19406848);   // 16 MB
  unsigned*       sync  = (unsigned*)(ws + 36184064);         // 256 B
  float*          xmlp  = (float*)(ws + 36184320);            // 32 MB (end ~68 MB)

  prep<<<4096, 256, 0, stream>>>(Whh, W1, bih, bhh, wbf, w1bf, bcomb);
  hipMemsetAsync(sync, 0, 256, stream);   // cnt=0, gen=0

  lstm_fused<<<NBLK, 512, 0, stream>>>(bx, Wih, bcomb, wbf, hb0, hb1,
                                       sync, sync + 32);

  // t=100 (even) wrote hout = hb1
  mlp1<<<dim3(128, 4), 256, 0, stream>>>(hb1, w1bf, b1, xmlp);
  mlp2<<<4096, 256, 0, stream>>>(xmlp, ba, W2, b2, out);
}